// Round 9
// baseline (129.785 us; speedup 1.0000x reference)
//
#include <hip/hip_runtime.h>

#define D_DIM 4096
#define N_DIM 1024
#define NNZ_F 131072
#define NNZP (NNZ_F + 3 * D_DIM)   // padded CSR capacity per factor (rows padded to x4)
#define K_F 4
#define NCHUNK 8               // one column-chunk per XCD
#define LPR 16                 // lanes per row (16B each -> 128 cols)
#define RPB 16                 // rows per block (16 rows x 16 lanes = 256 thr)
#define XS8 (N_DIM / 8)        // 128 uint4-slots (8 bf16) per row

#define T_TILES ((D_DIM / 64) * (N_DIM / 64))   // 1024 transpose tiles
#define TSTRIDE 132            // padded LDS stride for the 16x128 output tile

__device__ __forceinline__ unsigned short f2bf(float f) {
    union { float f; unsigned int u; } v; v.f = f;
    unsigned int r = v.u + 0x7fffu + ((v.u >> 16) & 1u);   // RNE, finite inputs
    return (unsigned short)(r >> 16);
}
__device__ __forceinline__ float bf_lo(unsigned int w) {
    return __uint_as_float(w << 16);
}
__device__ __forceinline__ float bf_hi(unsigned int w) {
    return __uint_as_float(w & 0xffff0000u);
}

// ---------- fused: transpose U [N,D] f32 -> UT [D,N] bf16  (+)  per-factor CSR
// count + padded scan + pad-slot zero-fill. grid = T_TILES + K_F blocks.
__global__ __launch_bounds__(1024) void fused_t_build_k(const float* __restrict__ in,
                                                        unsigned short* __restrict__ outb,
                                                        const int* __restrict__ rows,
                                                        int* __restrict__ row_ptr_g,
                                                        int* __restrict__ cursor_g,
                                                        int* __restrict__ csr_col_g,
                                                        float* __restrict__ csr_val_g) {
    __shared__ int s_cnt[4 * D_DIM];          // 64 KB: 4 sub-histograms OR transpose tile
    __shared__ int s_part[1024];
    const int tid = threadIdx.x;
    const int bid = blockIdx.x;

    if (bid < T_TILES) {
        // ---- transpose tile: 64x64, f32 in -> bf16 out ----
        float (*tile)[65] = (float (*)[65])s_cnt;
        const int gxi = bid & 63;            // tile along D
        const int gyi = bid >> 6;            // tile along N
        const int c0 = gxi * 64;             // offset in D
        const int r0 = gyi * 64;             // offset in N
        const int tx = tid & 63;
        const int ty = tid >> 6;             // 0..15
#pragma unroll
        for (int i = ty; i < 64; i += 16)
            tile[i][tx] = in[(size_t)(r0 + i) * D_DIM + c0 + tx];
        __syncthreads();
        const int px = (tid & 15) * 4;       // 4 n-locals per thread
        const int py = tid >> 4;             // 0..63 -> row of output tile
        ushort4 w;
        w.x = f2bf(tile[px + 0][py]);
        w.y = f2bf(tile[px + 1][py]);
        w.z = f2bf(tile[px + 2][py]);
        w.w = f2bf(tile[px + 3][py]);
        *(ushort4*)&outb[(size_t)(c0 + py) * N_DIM + r0 + px] = w;
        return;
    }

    // ---- CSR count + padded exclusive scan for factor f (one block per factor) ----
    const int f = bid - T_TILES;
    const int grp = (tid >> 8) & 3;          // 4 wave-groups, private histograms
#pragma unroll
    for (int k = 0; k < 16; ++k) s_cnt[tid + k * 1024] = 0;
    __syncthreads();

    int* h = s_cnt + grp * D_DIM;
    const int4* rp4 = (const int4*)(rows + (size_t)f * NNZ_F);
#pragma unroll 4
    for (int it = 0; it < NNZ_F / 4096; ++it) {      // 32 iters
        int4 r4 = rp4[(size_t)it * 1024 + tid];
        atomicAdd(&h[r4.x], 1);
        atomicAdd(&h[r4.y], 1);
        atomicAdd(&h[r4.z], 1);
        atomicAdd(&h[r4.w], 1);
    }
    __syncthreads();

    int c[4], plen[4];
    int part = 0;
#pragma unroll
    for (int k = 0; k < 4; ++k) {
        c[k] = s_cnt[tid * 4 + k] + s_cnt[D_DIM + tid * 4 + k]
             + s_cnt[2 * D_DIM + tid * 4 + k] + s_cnt[3 * D_DIM + tid * 4 + k];
        plen[k] = (c[k] + 3) & ~3;           // row length padded to multiple of 4
        part += plen[k];
    }
    s_part[tid] = part;
    __syncthreads();
    for (int off = 1; off < 1024; off <<= 1) {
        int v = (tid >= off) ? s_part[tid - off] : 0;
        __syncthreads();
        s_part[tid] += v;
        __syncthreads();
    }
    int excl = s_part[tid] - part;

    int*   rp  = row_ptr_g + (size_t)f * (D_DIM + 1);
    int*   cur = cursor_g + (size_t)f * D_DIM;
    int*   ccol = csr_col_g + (size_t)f * NNZP;
    float* cval = csr_val_g + (size_t)f * NNZP;
    const int b = tid * 4;
#pragma unroll
    for (int k = 0; k < 4; ++k) {
        rp[b + k] = excl;
        cur[b + k] = excl;
        // zero-fill the pad slots [excl+count, excl+plen)
        for (int p = excl + c[k]; p < excl + plen[k]; ++p) {
            ccol[p] = 0;
            cval[p] = 0.f;
        }
        excl += plen[k];
    }
    if (tid == 1023) rp[D_DIM] = excl;
}

// ---------- scatter all factors into padded CSR ----------
__global__ __launch_bounds__(1024) void scatter_all_k(const int* __restrict__ rows,
                                                      const int* __restrict__ cols,
                                                      const float* __restrict__ vals,
                                                      int* __restrict__ cursor,
                                                      int* __restrict__ csr_col,
                                                      float* __restrict__ csr_val) {
    const int f = blockIdx.x >> 7;                        // 128 blocks per factor
    const size_t j = (size_t)(blockIdx.x & 127) * 1024 + threadIdx.x;
    const size_t base = (size_t)f * NNZ_F;
    int r = rows[base + j];
    int p = atomicAdd(&cursor[(size_t)f * D_DIM + r], 1);
    csr_col[(size_t)f * NNZP + p] = cols[base + j];
    csr_val[(size_t)f * NNZP + p] = vals[base + j];
}

// ---------- chunked CSR spmm, bf16 input, LDS-free gather loop ----------
// chunk = blockIdx & 7 -> XCD-affine (1MB bf16 column slice per XCD L2).
// 16 rows/block, 16 lanes/row. CSR rows are 4-padded and 16B-aligned: each
// iteration one int4/float4 broadcast read (same addr across the 16 lanes,
// L1-resident) + FOUR independent 16B gathers in flight. No LDS, no barriers.
// FINAL: LDS-transpose the 16(d) x 128(n) f32 tile, add bias, write out[n][d].
template <bool FINAL>
__global__ __launch_bounds__(256) void spmm_chunk_k(const int* __restrict__ row_ptr,
                                                    const int4* __restrict__ col4,
                                                    const float4* __restrict__ val4,
                                                    const uint4* __restrict__ X,
                                                    uint4* __restrict__ Y,
                                                    float* __restrict__ out,
                                                    const float* __restrict__ bias) {
    __shared__ float tile_s[16 * TSTRIDE];    // used only in FINAL epilogue
    const int tid   = threadIdx.x;
    const int chunk = blockIdx.x & (NCHUNK - 1);
    const int rg    = blockIdx.x >> 3;
    const int r0    = rg * RPB;
    const int sub   = tid >> 4;               // row within group: 0..15
    const int lane  = tid & 15;               // uint4 slot within chunk
    const int slot  = chunk * LPR + lane;
    const int r     = r0 + sub;

    const int qs = row_ptr[r] >> 2;           // quad indices (rows 4-padded)
    const int qe = row_ptr[r + 1] >> 2;

    float acc[8];
#pragma unroll
    for (int k = 0; k < 8; ++k) acc[k] = 0.f;

    if (qs < qe) {
        int4   c = col4[qs];
        float4 v = val4[qs];
        for (int q = qs + 1; q <= qe; ++q) {
            // unconditional prefetch (buffer has slack; value unused on last iter)
            const int4   cn = col4[q];
            const float4 vn = val4[q];
            const uint4 x0 = X[(size_t)c.x * XS8 + slot];
            const uint4 x1 = X[(size_t)c.y * XS8 + slot];
            const uint4 x2 = X[(size_t)c.z * XS8 + slot];
            const uint4 x3 = X[(size_t)c.w * XS8 + slot];
            acc[0] += v.x * bf_lo(x0.x); acc[1] += v.x * bf_hi(x0.x);
            acc[2] += v.x * bf_lo(x0.y); acc[3] += v.x * bf_hi(x0.y);
            acc[4] += v.x * bf_lo(x0.z); acc[5] += v.x * bf_hi(x0.z);
            acc[6] += v.x * bf_lo(x0.w); acc[7] += v.x * bf_hi(x0.w);
            acc[0] += v.y * bf_lo(x1.x); acc[1] += v.y * bf_hi(x1.x);
            acc[2] += v.y * bf_lo(x1.y); acc[3] += v.y * bf_hi(x1.y);
            acc[4] += v.y * bf_lo(x1.z); acc[5] += v.y * bf_hi(x1.z);
            acc[6] += v.y * bf_lo(x1.w); acc[7] += v.y * bf_hi(x1.w);
            acc[0] += v.z * bf_lo(x2.x); acc[1] += v.z * bf_hi(x2.x);
            acc[2] += v.z * bf_lo(x2.y); acc[3] += v.z * bf_hi(x2.y);
            acc[4] += v.z * bf_lo(x2.z); acc[5] += v.z * bf_hi(x2.z);
            acc[6] += v.z * bf_lo(x2.w); acc[7] += v.z * bf_hi(x2.w);
            acc[0] += v.w * bf_lo(x3.x); acc[1] += v.w * bf_hi(x3.x);
            acc[2] += v.w * bf_lo(x3.y); acc[3] += v.w * bf_hi(x3.y);
            acc[4] += v.w * bf_lo(x3.z); acc[5] += v.w * bf_hi(x3.z);
            acc[6] += v.w * bf_lo(x3.w); acc[7] += v.w * bf_hi(x3.w);
            c = cn; v = vn;
        }
    }

    if (!FINAL) {
        uint4 o;
        o.x = (unsigned int)f2bf(acc[0]) | ((unsigned int)f2bf(acc[1]) << 16);
        o.y = (unsigned int)f2bf(acc[2]) | ((unsigned int)f2bf(acc[3]) << 16);
        o.z = (unsigned int)f2bf(acc[4]) | ((unsigned int)f2bf(acc[5]) << 16);
        o.w = (unsigned int)f2bf(acc[6]) | ((unsigned int)f2bf(acc[7]) << 16);
        Y[(size_t)r * XS8 + slot] = o;
    } else {
        // stage 16(d) x 128(n) f32 tile in LDS, then write transposed + bias
        float* tile = tile_s;
        const int wbase = sub * TSTRIDE + lane * 8;
        *(float4*)&tile[wbase]     = make_float4(acc[0], acc[1], acc[2], acc[3]);
        *(float4*)&tile[wbase + 4] = make_float4(acc[4], acc[5], acc[6], acc[7]);
        __syncthreads();
        const int n0 = chunk * (N_DIM / NCHUNK);
#pragma unroll
        for (int t = tid; t < 512; t += 256) {
            const int n_loc = t >> 2;         // 0..127
            const int q     = t & 3;          // d quad within the 16-row tile
            float4 o;
            o.x = tile[(q * 4 + 0) * TSTRIDE + n_loc];
            o.y = tile[(q * 4 + 1) * TSTRIDE + n_loc];
            o.z = tile[(q * 4 + 2) * TSTRIDE + n_loc];
            o.w = tile[(q * 4 + 3) * TSTRIDE + n_loc];
            const float4 bv = *(const float4*)&bias[r0 + q * 4];
            o.x += bv.x; o.y += bv.y; o.z += bv.z; o.w += bv.w;
            *(float4*)&out[(size_t)(n0 + n_loc) * D_DIM + r0 + q * 4] = o;
        }
    }
}

extern "C" void kernel_launch(void* const* d_in, const int* in_sizes, int n_in,
                              void* d_out, int out_size, void* d_ws, size_t ws_size,
                              hipStream_t stream) {
    const float* U    = (const float*)d_in[0];
    const float* bias = (const float*)d_in[1];
    const float* vals = (const float*)d_in[2];
    const int*   rows = (const int*)d_in[3];
    const int*   cols = (const int*)d_in[4];
    float* out = (float*)d_out;

    char* ws = (char*)d_ws;
    size_t off = 0;
    char* bufA = ws;                   off += (size_t)D_DIM * N_DIM * 2;   // 8 MB bf16
    char* bufB = ws + off;             off += (size_t)D_DIM * N_DIM * 2;   // 8 MB bf16
    int* row_ptr = (int*)(ws + off);   off += (size_t)K_F * (D_DIM + 1) * 4;
    off = (off + 15) & ~(size_t)15;
    int* cursor  = (int*)(ws + off);   off += (size_t)K_F * D_DIM * 4;
    int*   csr_col = (int*)(ws + off); off += (size_t)K_F * NNZP * 4 + 16;  // +slack
    float* csr_val = (float*)(ws + off); off += (size_t)K_F * NNZP * 4 + 16;

    const int grid_spmm = (D_DIM / RPB) * NCHUNK;   // 256 * 8 = 2048 blocks

    // K1: transpose U -> A (bf16) + CSR count/padded-scan/pad-fill (4 blocks), fused
    fused_t_build_k<<<T_TILES + K_F, 1024, 0, stream>>>(
        U, (unsigned short*)bufA, rows, row_ptr, cursor, csr_col, csr_val);

    // K2: scatter all factors
    scatter_all_k<<<K_F * (NNZ_F / 1024), 1024, 0, stream>>>(rows, cols, vals, cursor,
                                                             csr_col, csr_val);

    // K3: factor 3, A -> B
    spmm_chunk_k<false><<<grid_spmm, 256, 0, stream>>>(
        row_ptr + 3 * (D_DIM + 1), (const int4*)(csr_col + 3 * (size_t)NNZP),
        (const float4*)(csr_val + 3 * (size_t)NNZP),
        (const uint4*)bufA, (uint4*)bufB, nullptr, nullptr);
    // K4: factor 2, B -> A
    spmm_chunk_k<false><<<grid_spmm, 256, 0, stream>>>(
        row_ptr + 2 * (D_DIM + 1), (const int4*)(csr_col + 2 * (size_t)NNZP),
        (const float4*)(csr_val + 2 * (size_t)NNZP),
        (const uint4*)bufB, (uint4*)bufA, nullptr, nullptr);
    // K5: factor 1, A -> B
    spmm_chunk_k<false><<<grid_spmm, 256, 0, stream>>>(
        row_ptr + 1 * (D_DIM + 1), (const int4*)(csr_col + 1 * (size_t)NNZP),
        (const float4*)(csr_val + 1 * (size_t)NNZP),
        (const uint4*)bufA, (uint4*)bufB, nullptr, nullptr);
    // K6: factor 0, B -> out (transposed + bias, fused)
    spmm_chunk_k<true><<<grid_spmm, 256, 0, stream>>>(
        row_ptr + 0 * (D_DIM + 1), (const int4*)(csr_col + 0 * (size_t)NNZP),
        (const float4*)(csr_val + 0 * (size_t)NNZP),
        (const uint4*)bufB, nullptr, out, bias);
}

// Round 10
// 120.311 us; speedup vs baseline: 1.0787x; 1.0787x over previous
//
#include <hip/hip_runtime.h>

#define D_DIM 4096
#define N_DIM 1024
#define NNZ_F 131072
#define K_F 4
#define NCHUNK 8               // one column-chunk per XCD
#define LPR 16                 // lanes per row (16B each -> 128 cols)
#define RPB 16                 // rows per block (16 rows x 16 lanes = 256 thr)
#define MAXE 1024              // LDS staging capacity for CSR entries per block
#define XS8 (N_DIM / 8)        // 128 uint4-slots (8 bf16) per row

#define T_TILES ((D_DIM / 64) * (N_DIM / 64))   // 1024 transpose tiles
#define TSTRIDE 132            // padded LDS stride for the 16x128 output tile

typedef __attribute__((ext_vector_type(2))) float f32x2;

__device__ __forceinline__ unsigned short f2bf(float f) {
    union { float f; unsigned int u; } v; v.f = f;
    unsigned int r = v.u + 0x7fffu + ((v.u >> 16) & 1u);   // RNE, finite inputs
    return (unsigned short)(r >> 16);
}
__device__ __forceinline__ float bf_lo(unsigned int w) {
    return __uint_as_float(w << 16);
}
__device__ __forceinline__ float bf_hi(unsigned int w) {
    return __uint_as_float(w & 0xffff0000u);
}
// packed f32 FMA: a = x * v + a   (one VOP3P instruction for 2 lanes-worth)
__device__ __forceinline__ void pk_fma(f32x2& a, f32x2 x, f32x2 v) {
    asm volatile("v_pk_fma_f32 %0, %1, %2, %0" : "+v"(a) : "v"(x), "v"(v));
}
__device__ __forceinline__ f32x2 unpk(unsigned int w) {
    f32x2 r; r.x = bf_lo(w); r.y = bf_hi(w); return r;
}

// ---------- fused: transpose U [N,D] f32 -> UT [D,N] bf16  (+)  per-factor CSR count+scan
__global__ __launch_bounds__(1024) void fused_t_build_k(const float* __restrict__ in,
                                                        unsigned short* __restrict__ outb,
                                                        const int* __restrict__ rows,
                                                        int* __restrict__ row_ptr_g,
                                                        int* __restrict__ cursor_g) {
    __shared__ int s_cnt[4 * D_DIM];          // 64 KB: 4 sub-histograms OR transpose tile
    __shared__ int s_part[1024];
    const int tid = threadIdx.x;
    const int bid = blockIdx.x;

    if (bid < T_TILES) {
        // ---- transpose tile: 64x64, f32 in -> bf16 out ----
        float (*tile)[65] = (float (*)[65])s_cnt;
        const int gxi = bid & 63;            // tile along D
        const int gyi = bid >> 6;            // tile along N
        const int c0 = gxi * 64;             // offset in D
        const int r0 = gyi * 64;             // offset in N
        const int tx = tid & 63;
        const int ty = tid >> 6;             // 0..15
#pragma unroll
        for (int i = ty; i < 64; i += 16)
            tile[i][tx] = in[(size_t)(r0 + i) * D_DIM + c0 + tx];
        __syncthreads();
        const int px = (tid & 15) * 4;       // 4 n-locals per thread
        const int py = tid >> 4;             // 0..63 -> row of output tile
        ushort4 w;
        w.x = f2bf(tile[px + 0][py]);
        w.y = f2bf(tile[px + 1][py]);
        w.z = f2bf(tile[px + 2][py]);
        w.w = f2bf(tile[px + 3][py]);
        *(ushort4*)&outb[(size_t)(c0 + py) * N_DIM + r0 + px] = w;
        return;
    }

    // ---- CSR count + exclusive scan for factor f (one block per factor) ----
    const int f = bid - T_TILES;
    const int grp = (tid >> 8) & 3;          // 4 wave-groups, private histograms
#pragma unroll
    for (int k = 0; k < 16; ++k) s_cnt[tid + k * 1024] = 0;
    __syncthreads();

    int* h = s_cnt + grp * D_DIM;
    const int4* rp4 = (const int4*)(rows + (size_t)f * NNZ_F);
#pragma unroll 4
    for (int it = 0; it < NNZ_F / 4096; ++it) {      // 32 iters
        int4 r4 = rp4[(size_t)it * 1024 + tid];
        atomicAdd(&h[r4.x], 1);
        atomicAdd(&h[r4.y], 1);
        atomicAdd(&h[r4.z], 1);
        atomicAdd(&h[r4.w], 1);
    }
    __syncthreads();

    int c[4];
#pragma unroll
    for (int k = 0; k < 4; ++k)
        c[k] = s_cnt[tid * 4 + k] + s_cnt[D_DIM + tid * 4 + k]
             + s_cnt[2 * D_DIM + tid * 4 + k] + s_cnt[3 * D_DIM + tid * 4 + k];
    const int part = c[0] + c[1] + c[2] + c[3];
    s_part[tid] = part;
    __syncthreads();
    for (int off = 1; off < 1024; off <<= 1) {
        int v = (tid >= off) ? s_part[tid - off] : 0;
        __syncthreads();
        s_part[tid] += v;
        __syncthreads();
    }
    int excl = s_part[tid] - part;

    int* rp  = row_ptr_g + (size_t)f * (D_DIM + 1);
    int* cur = cursor_g + (size_t)f * D_DIM;
    int b = tid * 4;
#pragma unroll
    for (int k = 0; k < 4; ++k) {
        rp[b + k] = excl; cur[b + k] = excl; excl += c[k];
    }
    if (tid == 1023) rp[D_DIM] = NNZ_F;
}

// ---------- scatter all factors into CSR ----------
__global__ __launch_bounds__(1024) void scatter_all_k(const int* __restrict__ rows,
                                                      const int* __restrict__ cols,
                                                      const float* __restrict__ vals,
                                                      int* __restrict__ cursor,
                                                      int* __restrict__ csr_col,
                                                      float* __restrict__ csr_val) {
    const int f = blockIdx.x >> 7;                        // 128 blocks per factor
    const size_t j = (size_t)(blockIdx.x & 127) * 1024 + threadIdx.x;
    const size_t base = (size_t)f * NNZ_F;
    int r = rows[base + j];
    int p = atomicAdd(&cursor[(size_t)f * D_DIM + r], 1);
    csr_col[base + p] = cols[base + j];
    csr_val[base + p] = vals[base + j];
}

// ---------- chunked CSR spmm, bf16 input, 16B gathers, packed-f32 FMA ----------
// chunk = blockIdx & 7 -> XCD-affine; each XCD's L2 holds its 1MB bf16 column slice.
// 16 rows/block, 16 lanes/row; CSR staged in LDS (lgkm pipe, cooperative+coalesced).
// Inner loop per nnz: 1 gather (16B) + 8 unpack + 4 v_pk_fma_f32.
// FINAL: LDS-transpose the block's 16(d) x 128(n) f32 tile, add bias, write out[n][d].
template <bool FINAL>
__global__ __launch_bounds__(256) void spmm_chunk_k(const int* __restrict__ row_ptr,
                                                    const int* __restrict__ csr_col,
                                                    const float* __restrict__ csr_val,
                                                    const uint4* __restrict__ X,
                                                    uint4* __restrict__ Y,
                                                    float* __restrict__ out,
                                                    const float* __restrict__ bias) {
    __shared__ float smem[16 * TSTRIDE];      // 8448 B; covers CSR staging + out tile
    int*   s_col = (int*)smem;                // [MAXE]
    float* s_val = smem + MAXE;               // [MAXE]
    int*   s_ptr = (int*)(smem + 2 * MAXE);   // [RPB+1]

    const int tid   = threadIdx.x;
    const int chunk = blockIdx.x & (NCHUNK - 1);
    const int rg    = blockIdx.x >> 3;
    const int r0    = rg * RPB;
    const int sub   = tid >> 4;               // row within group: 0..15
    const int lane  = tid & 15;               // uint4 slot within chunk
    const int slot  = chunk * LPR + lane;
    const int r     = r0 + sub;

    if (tid <= RPB) s_ptr[tid] = row_ptr[r0 + tid];
    __syncthreads();
    const int base  = s_ptr[0];
    const int total = s_ptr[RPB] - base;
    const int start = s_ptr[sub] - base;
    const int end_  = s_ptr[sub + 1] - base;

    f32x2 a0 = {0.f, 0.f}, a1 = {0.f, 0.f}, a2 = {0.f, 0.f}, a3 = {0.f, 0.f};

    for (int cb2 = 0; cb2 < total; cb2 += MAXE) {
        int cnt = total - cb2;
        if (cnt > MAXE) cnt = MAXE;
        for (int t = tid; t < cnt; t += 256) {
            s_col[t] = csr_col[base + cb2 + t];
            s_val[t] = csr_val[base + cb2 + t];
        }
        __syncthreads();
        int js = start > cb2 ? start : cb2;
        int je = end_ < cb2 + cnt ? end_ : cb2 + cnt;
        if (js < je) {
            int   jj = js - cb2;
            uint4 x  = X[(size_t)s_col[jj] * XS8 + slot];
            float v  = s_val[jj];
#pragma unroll 2
            for (int j = js + 1; j < je; ++j) {
                const int   jn = j - cb2;
                const uint4 xn = X[(size_t)s_col[jn] * XS8 + slot];
                const float vn = s_val[jn];
                const f32x2 vv = {v, v};
                pk_fma(a0, unpk(x.x), vv);
                pk_fma(a1, unpk(x.y), vv);
                pk_fma(a2, unpk(x.z), vv);
                pk_fma(a3, unpk(x.w), vv);
                x = xn; v = vn;
            }
            const f32x2 vv = {v, v};
            pk_fma(a0, unpk(x.x), vv);
            pk_fma(a1, unpk(x.y), vv);
            pk_fma(a2, unpk(x.z), vv);
            pk_fma(a3, unpk(x.w), vv);
        }
        __syncthreads();
    }

    if (!FINAL) {
        uint4 o;
        o.x = (unsigned int)f2bf(a0.x) | ((unsigned int)f2bf(a0.y) << 16);
        o.y = (unsigned int)f2bf(a1.x) | ((unsigned int)f2bf(a1.y) << 16);
        o.z = (unsigned int)f2bf(a2.x) | ((unsigned int)f2bf(a2.y) << 16);
        o.w = (unsigned int)f2bf(a3.x) | ((unsigned int)f2bf(a3.y) << 16);
        Y[(size_t)r * XS8 + slot] = o;
    } else {
        // stage 16(d) x 128(n) f32 tile in LDS (stride 132), write transposed + bias
        __syncthreads();                      // all s_col/s_val consumers done
        float* tile = smem;
        const int wbase = sub * TSTRIDE + lane * 8;
        *(float4*)&tile[wbase]     = make_float4(a0.x, a0.y, a1.x, a1.y);
        *(float4*)&tile[wbase + 4] = make_float4(a2.x, a2.y, a3.x, a3.y);
        __syncthreads();
        const int n0 = chunk * (N_DIM / NCHUNK);
#pragma unroll
        for (int t = tid; t < 512; t += 256) {
            const int n_loc = t >> 2;         // 0..127
            const int q     = t & 3;          // d quad within the 16-row tile
            float4 o;
            o.x = tile[(q * 4 + 0) * TSTRIDE + n_loc];
            o.y = tile[(q * 4 + 1) * TSTRIDE + n_loc];
            o.z = tile[(q * 4 + 2) * TSTRIDE + n_loc];
            o.w = tile[(q * 4 + 3) * TSTRIDE + n_loc];
            const float4 bv = *(const float4*)&bias[r0 + q * 4];
            o.x += bv.x; o.y += bv.y; o.z += bv.z; o.w += bv.w;
            *(float4*)&out[(size_t)(n0 + n_loc) * D_DIM + r0 + q * 4] = o;
        }
    }
}

extern "C" void kernel_launch(void* const* d_in, const int* in_sizes, int n_in,
                              void* d_out, int out_size, void* d_ws, size_t ws_size,
                              hipStream_t stream) {
    const float* U    = (const float*)d_in[0];
    const float* bias = (const float*)d_in[1];
    const float* vals = (const float*)d_in[2];
    const int*   rows = (const int*)d_in[3];
    const int*   cols = (const int*)d_in[4];
    float* out = (float*)d_out;

    char* ws = (char*)d_ws;
    size_t off = 0;
    char* bufA = ws;                   off += (size_t)D_DIM * N_DIM * 2;   // 8 MB bf16
    char* bufB = ws + off;             off += (size_t)D_DIM * N_DIM * 2;   // 8 MB bf16
    int* row_ptr = (int*)(ws + off);   off += (size_t)K_F * (D_DIM + 1) * 4;
    off = (off + 15) & ~(size_t)15;
    int* cursor  = (int*)(ws + off);   off += (size_t)K_F * D_DIM * 4;
    int*   csr_col = (int*)(ws + off); off += (size_t)K_F * NNZ_F * 4;
    float* csr_val = (float*)(ws + off); off += (size_t)K_F * NNZ_F * 4;

    const int grid_spmm = (D_DIM / RPB) * NCHUNK;   // 256 * 8 = 2048 blocks

    // K1: transpose U -> A (bf16) + CSR count/scan (4 blocks), fused
    fused_t_build_k<<<T_TILES + K_F, 1024, 0, stream>>>(
        U, (unsigned short*)bufA, rows, row_ptr, cursor);

    // K2: scatter all factors
    scatter_all_k<<<K_F * (NNZ_F / 1024), 1024, 0, stream>>>(rows, cols, vals, cursor,
                                                             csr_col, csr_val);

    // K3: factor 3, A -> B
    spmm_chunk_k<false><<<grid_spmm, 256, 0, stream>>>(
        row_ptr + 3 * (D_DIM + 1), csr_col + 3 * (size_t)NNZ_F, csr_val + 3 * (size_t)NNZ_F,
        (const uint4*)bufA, (uint4*)bufB, nullptr, nullptr);
    // K4: factor 2, B -> A
    spmm_chunk_k<false><<<grid_spmm, 256, 0, stream>>>(
        row_ptr + 2 * (D_DIM + 1), csr_col + 2 * (size_t)NNZ_F, csr_val + 2 * (size_t)NNZ_F,
        (const uint4*)bufB, (uint4*)bufA, nullptr, nullptr);
    // K5: factor 1, A -> B
    spmm_chunk_k<false><<<grid_spmm, 256, 0, stream>>>(
        row_ptr + 1 * (D_DIM + 1), csr_col + 1 * (size_t)NNZ_F, csr_val + 1 * (size_t)NNZ_F,
        (const uint4*)bufA, (uint4*)bufB, nullptr, nullptr);
    // K6: factor 0, B -> out (transposed + bias, fused)
    spmm_chunk_k<true><<<grid_spmm, 256, 0, stream>>>(
        row_ptr + 0 * (D_DIM + 1), csr_col + 0 * (size_t)NNZ_F, csr_val + 0 * (size_t)NNZ_F,
        (const uint4*)bufB, nullptr, out, bias);
}

// Round 11
// 111.298 us; speedup vs baseline: 1.1661x; 1.0810x over previous
//
#include <hip/hip_runtime.h>

#define D_DIM 4096
#define N_DIM 1024
#define NNZ_F 131072
#define K_F 4
#define NCHUNK 8               // one column-chunk per XCD
#define LPR 16                 // lanes per row (16B each -> 128 cols)
#define RPB 16                 // rows per block (16 rows x 16 lanes = 256 thr)
#define MAXE 1024              // LDS staging capacity for CSR entries per block
#define XS8 (N_DIM / 8)        // 128 uint4-slots (8 bf16) per row

#define T_TILES ((D_DIM / 64) * (N_DIM / 64))   // 1024 transpose tiles
#define TSTRIDE 132            // padded LDS stride for the 16x128 output tile

__device__ __forceinline__ unsigned short f2bf(float f) {
    union { float f; unsigned int u; } v; v.f = f;
    unsigned int r = v.u + 0x7fffu + ((v.u >> 16) & 1u);   // RNE, finite inputs
    return (unsigned short)(r >> 16);
}
__device__ __forceinline__ float bf_lo(unsigned int w) {
    return __uint_as_float(w << 16);
}
__device__ __forceinline__ float bf_hi(unsigned int w) {
    return __uint_as_float(w & 0xffff0000u);
}

// ---------- fused: transpose U [N,D] f32 -> UT [D,N] bf16  (+)  per-factor CSR count+scan
__global__ __launch_bounds__(1024) void fused_t_build_k(const float* __restrict__ in,
                                                        unsigned short* __restrict__ outb,
                                                        const int* __restrict__ rows,
                                                        int* __restrict__ row_ptr_g,
                                                        int* __restrict__ cursor_g) {
    __shared__ int s_cnt[4 * D_DIM];          // 64 KB: 4 sub-histograms OR transpose tile
    __shared__ int s_part[1024];
    const int tid = threadIdx.x;
    const int bid = blockIdx.x;

    if (bid < T_TILES) {
        // ---- transpose tile: 64x64, f32 in -> bf16 out ----
        float (*tile)[65] = (float (*)[65])s_cnt;
        const int gxi = bid & 63;            // tile along D
        const int gyi = bid >> 6;            // tile along N
        const int c0 = gxi * 64;             // offset in D
        const int r0 = gyi * 64;             // offset in N
        const int tx = tid & 63;
        const int ty = tid >> 6;             // 0..15
#pragma unroll
        for (int i = ty; i < 64; i += 16)
            tile[i][tx] = in[(size_t)(r0 + i) * D_DIM + c0 + tx];
        __syncthreads();
        const int px = (tid & 15) * 4;       // 4 n-locals per thread
        const int py = tid >> 4;             // 0..63 -> row of output tile
        ushort4 w;
        w.x = f2bf(tile[px + 0][py]);
        w.y = f2bf(tile[px + 1][py]);
        w.z = f2bf(tile[px + 2][py]);
        w.w = f2bf(tile[px + 3][py]);
        *(ushort4*)&outb[(size_t)(c0 + py) * N_DIM + r0 + px] = w;
        return;
    }

    // ---- CSR count + exclusive scan for factor f (one block per factor) ----
    const int f = bid - T_TILES;
    const int grp = (tid >> 8) & 3;          // 4 wave-groups, private histograms
#pragma unroll
    for (int k = 0; k < 16; ++k) s_cnt[tid + k * 1024] = 0;
    __syncthreads();

    int* h = s_cnt + grp * D_DIM;
    const int4* rp4 = (const int4*)(rows + (size_t)f * NNZ_F);
#pragma unroll 4
    for (int it = 0; it < NNZ_F / 4096; ++it) {      // 32 iters
        int4 r4 = rp4[(size_t)it * 1024 + tid];
        atomicAdd(&h[r4.x], 1);
        atomicAdd(&h[r4.y], 1);
        atomicAdd(&h[r4.z], 1);
        atomicAdd(&h[r4.w], 1);
    }
    __syncthreads();

    int c[4];
#pragma unroll
    for (int k = 0; k < 4; ++k)
        c[k] = s_cnt[tid * 4 + k] + s_cnt[D_DIM + tid * 4 + k]
             + s_cnt[2 * D_DIM + tid * 4 + k] + s_cnt[3 * D_DIM + tid * 4 + k];
    const int part = c[0] + c[1] + c[2] + c[3];
    s_part[tid] = part;
    __syncthreads();
    for (int off = 1; off < 1024; off <<= 1) {
        int v = (tid >= off) ? s_part[tid - off] : 0;
        __syncthreads();
        s_part[tid] += v;
        __syncthreads();
    }
    int excl = s_part[tid] - part;

    int* rp  = row_ptr_g + (size_t)f * (D_DIM + 1);
    int* cur = cursor_g + (size_t)f * D_DIM;
    int b = tid * 4;
#pragma unroll
    for (int k = 0; k < 4; ++k) {
        rp[b + k] = excl; cur[b + k] = excl; excl += c[k];
    }
    if (tid == 1023) rp[D_DIM] = NNZ_F;
}

// ---------- scatter all factors into CSR ----------
__global__ __launch_bounds__(1024) void scatter_all_k(const int* __restrict__ rows,
                                                      const int* __restrict__ cols,
                                                      const float* __restrict__ vals,
                                                      int* __restrict__ cursor,
                                                      int* __restrict__ csr_col,
                                                      float* __restrict__ csr_val) {
    const int f = blockIdx.x >> 7;                        // 128 blocks per factor
    const size_t j = (size_t)(blockIdx.x & 127) * 1024 + threadIdx.x;
    const size_t base = (size_t)f * NNZ_F;
    int r = rows[base + j];
    int p = atomicAdd(&cursor[(size_t)f * D_DIM + r], 1);
    csr_col[base + p] = cols[base + j];
    csr_val[base + p] = vals[base + j];
}

// ---------- chunked CSR spmm, bf16 input, paired 16B gathers ----------
// chunk = blockIdx & 7 -> XCD-affine; each XCD's L2 holds its 1MB bf16 column slice.
// 16 rows/block, 16 lanes/row; CSR staged in LDS. Inner loop processes TWO nnz
// per iteration with both gathers issued before any FMA (2-4 loads in flight per
// thread -> past the BW*latency threshold). 32-bit byte offsets: (c<<11)+slot*16.
// FINAL: LDS-transpose the 16(d) x 128(n) f32 tile, add bias, write out[n][d].
template <bool FINAL>
__global__ __launch_bounds__(256) void spmm_chunk_k(const int* __restrict__ row_ptr,
                                                    const int* __restrict__ csr_col,
                                                    const float* __restrict__ csr_val,
                                                    const char* __restrict__ Xb,
                                                    uint4* __restrict__ Y,
                                                    float* __restrict__ out,
                                                    const float* __restrict__ bias) {
    __shared__ float smem[16 * TSTRIDE];      // 8448 B; covers CSR staging + out tile
    int*   s_col = (int*)smem;                // [MAXE]
    float* s_val = smem + MAXE;               // [MAXE]
    int*   s_ptr = (int*)(smem + 2 * MAXE);   // [RPB+1]

    const int tid   = threadIdx.x;
    const int chunk = blockIdx.x & (NCHUNK - 1);
    const int rg    = blockIdx.x >> 3;
    const int r0    = rg * RPB;
    const int sub   = tid >> 4;               // row within group: 0..15
    const int lane  = tid & 15;               // uint4 slot within chunk
    const int slot  = chunk * LPR + lane;
    const unsigned sl16 = (unsigned)slot * 16u;
    const int r     = r0 + sub;

    if (tid <= RPB) s_ptr[tid] = row_ptr[r0 + tid];
    __syncthreads();
    const int base  = s_ptr[0];
    const int total = s_ptr[RPB] - base;
    const int start = s_ptr[sub] - base;
    const int end_  = s_ptr[sub + 1] - base;

    float acc[8];
#pragma unroll
    for (int k = 0; k < 8; ++k) acc[k] = 0.f;

    for (int cb2 = 0; cb2 < total; cb2 += MAXE) {
        int cnt = total - cb2;
        if (cnt > MAXE) cnt = MAXE;
        for (int t = tid; t < cnt; t += 256) {
            s_col[t] = csr_col[base + cb2 + t];
            s_val[t] = csr_val[base + cb2 + t];
        }
        __syncthreads();
        const int js = start > cb2 ? start : cb2;
        const int je = end_ < cb2 + cnt ? end_ : cb2 + cnt;
        int j = js;
#pragma unroll 2
        for (; j + 1 < je; j += 2) {
            const int j0 = j - cb2;
            const unsigned o0 = ((unsigned)s_col[j0] << 11) + sl16;
            const unsigned o1 = ((unsigned)s_col[j0 + 1] << 11) + sl16;
            const uint4 x0 = *(const uint4*)(Xb + o0);
            const uint4 x1 = *(const uint4*)(Xb + o1);
            const float v0 = s_val[j0];
            const float v1 = s_val[j0 + 1];
            acc[0] += v0 * bf_lo(x0.x); acc[1] += v0 * bf_hi(x0.x);
            acc[2] += v0 * bf_lo(x0.y); acc[3] += v0 * bf_hi(x0.y);
            acc[4] += v0 * bf_lo(x0.z); acc[5] += v0 * bf_hi(x0.z);
            acc[6] += v0 * bf_lo(x0.w); acc[7] += v0 * bf_hi(x0.w);
            acc[0] += v1 * bf_lo(x1.x); acc[1] += v1 * bf_hi(x1.x);
            acc[2] += v1 * bf_lo(x1.y); acc[3] += v1 * bf_hi(x1.y);
            acc[4] += v1 * bf_lo(x1.z); acc[5] += v1 * bf_hi(x1.z);
            acc[6] += v1 * bf_lo(x1.w); acc[7] += v1 * bf_hi(x1.w);
        }
        if (j < je) {
            const int j0 = j - cb2;
            const unsigned o0 = ((unsigned)s_col[j0] << 11) + sl16;
            const uint4 x0 = *(const uint4*)(Xb + o0);
            const float v0 = s_val[j0];
            acc[0] += v0 * bf_lo(x0.x); acc[1] += v0 * bf_hi(x0.x);
            acc[2] += v0 * bf_lo(x0.y); acc[3] += v0 * bf_hi(x0.y);
            acc[4] += v0 * bf_lo(x0.z); acc[5] += v0 * bf_hi(x0.z);
            acc[6] += v0 * bf_lo(x0.w); acc[7] += v0 * bf_hi(x0.w);
        }
        __syncthreads();
    }

    if (!FINAL) {
        uint4 o;
        o.x = (unsigned int)f2bf(acc[0]) | ((unsigned int)f2bf(acc[1]) << 16);
        o.y = (unsigned int)f2bf(acc[2]) | ((unsigned int)f2bf(acc[3]) << 16);
        o.z = (unsigned int)f2bf(acc[4]) | ((unsigned int)f2bf(acc[5]) << 16);
        o.w = (unsigned int)f2bf(acc[6]) | ((unsigned int)f2bf(acc[7]) << 16);
        Y[(size_t)r * XS8 + slot] = o;
    } else {
        // stage 16(d) x 128(n) f32 tile in LDS (stride 132), write transposed + bias
        __syncthreads();                      // all s_col/s_val consumers done
        float* tile = smem;
        const int wbase = sub * TSTRIDE + lane * 8;
        *(float4*)&tile[wbase]     = make_float4(acc[0], acc[1], acc[2], acc[3]);
        *(float4*)&tile[wbase + 4] = make_float4(acc[4], acc[5], acc[6], acc[7]);
        __syncthreads();
        const int n0 = chunk * (N_DIM / NCHUNK);
#pragma unroll
        for (int t = tid; t < 512; t += 256) {
            const int n_loc = t >> 2;         // 0..127
            const int q     = t & 3;          // d quad within the 16-row tile
            float4 o;
            o.x = tile[(q * 4 + 0) * TSTRIDE + n_loc];
            o.y = tile[(q * 4 + 1) * TSTRIDE + n_loc];
            o.z = tile[(q * 4 + 2) * TSTRIDE + n_loc];
            o.w = tile[(q * 4 + 3) * TSTRIDE + n_loc];
            const float4 bv = *(const float4*)&bias[r0 + q * 4];
            o.x += bv.x; o.y += bv.y; o.z += bv.z; o.w += bv.w;
            *(float4*)&out[(size_t)(n0 + n_loc) * D_DIM + r0 + q * 4] = o;
        }
    }
}

extern "C" void kernel_launch(void* const* d_in, const int* in_sizes, int n_in,
                              void* d_out, int out_size, void* d_ws, size_t ws_size,
                              hipStream_t stream) {
    const float* U    = (const float*)d_in[0];
    const float* bias = (const float*)d_in[1];
    const float* vals = (const float*)d_in[2];
    const int*   rows = (const int*)d_in[3];
    const int*   cols = (const int*)d_in[4];
    float* out = (float*)d_out;

    char* ws = (char*)d_ws;
    size_t off = 0;
    char* bufA = ws;                   off += (size_t)D_DIM * N_DIM * 2;   // 8 MB bf16
    char* bufB = ws + off;             off += (size_t)D_DIM * N_DIM * 2;   // 8 MB bf16
    int* row_ptr = (int*)(ws + off);   off += (size_t)K_F * (D_DIM + 1) * 4;
    off = (off + 15) & ~(size_t)15;
    int* cursor  = (int*)(ws + off);   off += (size_t)K_F * D_DIM * 4;
    int*   csr_col = (int*)(ws + off); off += (size_t)K_F * NNZ_F * 4;
    float* csr_val = (float*)(ws + off); off += (size_t)K_F * NNZ_F * 4;

    const int grid_spmm = (D_DIM / RPB) * NCHUNK;   // 256 * 8 = 2048 blocks

    // K1: transpose U -> A (bf16) + CSR count/scan (4 blocks), fused
    fused_t_build_k<<<T_TILES + K_F, 1024, 0, stream>>>(
        U, (unsigned short*)bufA, rows, row_ptr, cursor);

    // K2: scatter all factors
    scatter_all_k<<<K_F * (NNZ_F / 1024), 1024, 0, stream>>>(rows, cols, vals, cursor,
                                                             csr_col, csr_val);

    // K3: factor 3, A -> B
    spmm_chunk_k<false><<<grid_spmm, 256, 0, stream>>>(
        row_ptr + 3 * (D_DIM + 1), csr_col + 3 * (size_t)NNZ_F, csr_val + 3 * (size_t)NNZ_F,
        (const char*)bufA, (uint4*)bufB, nullptr, nullptr);
    // K4: factor 2, B -> A
    spmm_chunk_k<false><<<grid_spmm, 256, 0, stream>>>(
        row_ptr + 2 * (D_DIM + 1), csr_col + 2 * (size_t)NNZ_F, csr_val + 2 * (size_t)NNZ_F,
        (const char*)bufB, (uint4*)bufA, nullptr, nullptr);
    // K5: factor 1, A -> B
    spmm_chunk_k<false><<<grid_spmm, 256, 0, stream>>>(
        row_ptr + 1 * (D_DIM + 1), csr_col + 1 * (size_t)NNZ_F, csr_val + 1 * (size_t)NNZ_F,
        (const char*)bufA, (uint4*)bufB, nullptr, nullptr);
    // K6: factor 0, B -> out (transposed + bias, fused)
    spmm_chunk_k<true><<<grid_spmm, 256, 0, stream>>>(
        row_ptr + 0 * (D_DIM + 1), csr_col + 0 * (size_t)NNZ_F, csr_val + 0 * (size_t)NNZ_F,
        (const char*)bufB, nullptr, out, bias);
}

// Round 12
// 111.222 us; speedup vs baseline: 1.1669x; 1.0007x over previous
//
#include <hip/hip_runtime.h>

#define D_DIM 4096
#define N_DIM 1024
#define NNZ_F 131072
#define K_F 4
#define NCHUNK 8               // one column-chunk per XCD
#define LPR 16                 // lanes per row (16B each -> 128 cols)
#define RPB 16                 // rows per block (16 rows x 16 lanes = 256 thr)
#define MAXE 1024              // LDS staging capacity for CSR entries per block
#define XS8 (N_DIM / 8)        // 128 uint4-slots (8 bf16) per row

#define T_TILES ((D_DIM / 64) * (N_DIM / 64))   // 1024 transpose tiles
#define TSTRIDE 132            // padded LDS stride for the 16x128 output tile

__device__ __forceinline__ unsigned short f2bf(float f) {
    union { float f; unsigned int u; } v; v.f = f;
    unsigned int r = v.u + 0x7fffu + ((v.u >> 16) & 1u);   // RNE, finite inputs
    return (unsigned short)(r >> 16);
}
__device__ __forceinline__ float bf_lo(unsigned int w) {
    return __uint_as_float(w << 16);
}
__device__ __forceinline__ float bf_hi(unsigned int w) {
    return __uint_as_float(w & 0xffff0000u);
}

// ---------- fused: per-factor CSR build (bid<K_F, FIRST so it overlaps) +
//            transpose U [N,D] f32 -> UT [D,N] bf16 (remaining 1024 blocks).
// Factors 1..3: rows counting-sorted by nnz length -> near-equal row lengths per
// spmm block (kills wave-max divergence). Factor 0: identity layout (the fused
// output-transpose epilogue needs contiguous aligned rows).
__global__ __launch_bounds__(1024) void fused_t_build_k(const float* __restrict__ in,
                                                        unsigned short* __restrict__ outb,
                                                        const int* __restrict__ rows,
                                                        int* __restrict__ row_ptr_g,
                                                        int* __restrict__ cursor_g,
                                                        int* __restrict__ srow_g) {
    __shared__ int s_cnt[4 * D_DIM];          // 64 KB: 4 sub-histograms OR transpose tile
    __shared__ int s_part[1024];              // scan buffer (factor-0 path)
    const int tid = threadIdx.x;
    const int bid = blockIdx.x;

    if (bid >= K_F) {
        // ---- transpose tile: 64x64, f32 in -> bf16 out ----
        const int tb = bid - K_F;
        float (*tile)[65] = (float (*)[65])s_cnt;
        const int gxi = tb & 63;             // tile along D
        const int gyi = tb >> 6;             // tile along N
        const int c0 = gxi * 64;             // offset in D
        const int r0 = gyi * 64;             // offset in N
        const int tx = tid & 63;
        const int ty = tid >> 6;             // 0..15
#pragma unroll
        for (int i = ty; i < 64; i += 16)
            tile[i][tx] = in[(size_t)(r0 + i) * D_DIM + c0 + tx];
        __syncthreads();
        const int px = (tid & 15) * 4;       // 4 n-locals per thread
        const int py = tid >> 4;             // 0..63 -> row of output tile
        ushort4 w;
        w.x = f2bf(tile[px + 0][py]);
        w.y = f2bf(tile[px + 1][py]);
        w.z = f2bf(tile[px + 2][py]);
        w.w = f2bf(tile[px + 3][py]);
        *(ushort4*)&outb[(size_t)(c0 + py) * N_DIM + r0 + px] = w;
        return;
    }

    // ---- CSR count for factor f (one block per factor) ----
    const int f = bid;
    const int grp = (tid >> 8) & 3;          // 4 wave-groups, private histograms
#pragma unroll
    for (int k = 0; k < 16; ++k) s_cnt[tid + k * 1024] = 0;
    __syncthreads();

    int* h = s_cnt + grp * D_DIM;
    const int4* rp4 = (const int4*)(rows + (size_t)f * NNZ_F);
#pragma unroll 4
    for (int it = 0; it < NNZ_F / 4096; ++it) {      // 32 iters
        int4 r4 = rp4[(size_t)it * 1024 + tid];
        atomicAdd(&h[r4.x], 1);
        atomicAdd(&h[r4.y], 1);
        atomicAdd(&h[r4.z], 1);
        atomicAdd(&h[r4.w], 1);
    }
    __syncthreads();

    int c[4];
#pragma unroll
    for (int k = 0; k < 4; ++k)
        c[k] = s_cnt[tid * 4 + k] + s_cnt[D_DIM + tid * 4 + k]
             + s_cnt[2 * D_DIM + tid * 4 + k] + s_cnt[3 * D_DIM + tid * 4 + k];
    const int b = tid * 4;

    int*   rp   = row_ptr_g + (size_t)f * (D_DIM + 1);
    int*   cur  = cursor_g + (size_t)f * D_DIM;
    int*   srow = srow_g + (size_t)f * D_DIM;

    if (f == 0) {
        // identity layout: plain exclusive scan
        const int part = c[0] + c[1] + c[2] + c[3];
        s_part[tid] = part;
        __syncthreads();
        for (int off = 1; off < 1024; off <<= 1) {
            int v = (tid >= off) ? s_part[tid - off] : 0;
            __syncthreads();
            s_part[tid] += v;
            __syncthreads();
        }
        int excl = s_part[tid] - part;
#pragma unroll
        for (int k = 0; k < 4; ++k) {
            rp[b + k] = excl; cur[b + k] = excl; srow[b + k] = b + k; excl += c[k];
        }
        if (tid == 1023) rp[D_DIM] = NNZ_F;
        return;
    }

    // counting sort by row length (256 bins); CSR laid out in sorted order.
    __syncthreads();                          // merge-readers done; reuse s_cnt tail
    int* hist = s_cnt + 4096;
    int* binc = s_cnt + 4352;
    int* sA   = s_cnt + 4608;                 // inclusive scan of hist
    int* sB   = s_cnt + 4864;                 // inclusive scan of hist[l]*l
    if (tid < 256) { hist[tid] = 0; binc[tid] = 0; }
    __syncthreads();
#pragma unroll
    for (int k = 0; k < 4; ++k) {
        int l = c[k] > 255 ? 255 : c[k];
        atomicAdd(&hist[l], 1);
    }
    __syncthreads();
    if (tid < 256) { int hv = hist[tid]; sA[tid] = hv; sB[tid] = hv * tid; }
    __syncthreads();
    for (int off = 1; off < 256; off <<= 1) {
        int a = 0, bb = 0;
        if (tid < 256 && tid >= off) { a = sA[tid - off]; bb = sB[tid - off]; }
        __syncthreads();
        if (tid < 256) { sA[tid] += a; sB[tid] += bb; }
        __syncthreads();
    }
#pragma unroll
    for (int k = 0; k < 4; ++k) {
        const int l = c[k] > 255 ? 255 : c[k];
        const int idx = atomicAdd(&binc[l], 1);
        const int pos    = sA[l] - hist[l] + idx;            // exclusive bin start + idx
        const int startp = sB[l] - hist[l] * l + idx * l;    // exclusive len-offset
        srow[pos] = b + k;
        rp[pos] = startp;
        cur[b + k] = startp;
    }
    if (tid == 1023) rp[D_DIM] = NNZ_F;
}

// ---------- scatter all factors into (possibly permuted) CSR ----------
__global__ __launch_bounds__(1024) void scatter_all_k(const int* __restrict__ rows,
                                                      const int* __restrict__ cols,
                                                      const float* __restrict__ vals,
                                                      int* __restrict__ cursor,
                                                      int* __restrict__ csr_col,
                                                      float* __restrict__ csr_val) {
    const int f = blockIdx.x >> 7;                        // 128 blocks per factor
    const size_t j = (size_t)(blockIdx.x & 127) * 1024 + threadIdx.x;
    const size_t base = (size_t)f * NNZ_F;
    int r = rows[base + j];
    int p = atomicAdd(&cursor[(size_t)f * D_DIM + r], 1);
    csr_col[base + p] = cols[base + j];
    csr_val[base + p] = vals[base + j];
}

// ---------- chunked CSR spmm, bf16 input, paired 16B gathers ----------
// chunk = blockIdx & 7 -> XCD-affine; 16 rows/block, 16 lanes/row. Rows are the
// length-sorted positions r0..r0+15 (near-equal lengths -> wave max ~= mean);
// actual output row = s_srow[sub]. CSR entries for the block are contiguous.
// FINAL: identity layout; LDS-transpose 16(d) x 128(n) tile + bias -> out[n][d].
template <bool FINAL>
__global__ __launch_bounds__(256) void spmm_chunk_k(const int* __restrict__ row_ptr,
                                                    const int* __restrict__ sorted_rows,
                                                    const int* __restrict__ csr_col,
                                                    const float* __restrict__ csr_val,
                                                    const char* __restrict__ Xb,
                                                    uint4* __restrict__ Y,
                                                    float* __restrict__ out,
                                                    const float* __restrict__ bias) {
    __shared__ float smem[16 * TSTRIDE];      // 8448 B; CSR staging + out tile
    int*   s_col  = (int*)smem;               // [MAXE]
    float* s_val  = smem + MAXE;              // [MAXE]
    int*   s_ptr  = (int*)(smem + 2 * MAXE);  // [RPB+1]
    int*   s_srow = (int*)(smem + 2 * MAXE + 32);  // [RPB]

    const int tid   = threadIdx.x;
    const int chunk = blockIdx.x & (NCHUNK - 1);
    const int rg    = blockIdx.x >> 3;
    const int r0    = rg * RPB;
    const int sub   = tid >> 4;               // row within group: 0..15
    const int lane  = tid & 15;               // uint4 slot within chunk
    const int slot  = chunk * LPR + lane;
    const unsigned sl16 = (unsigned)slot * 16u;

    if (tid <= RPB) s_ptr[tid] = row_ptr[r0 + tid];
    if (tid < RPB)  s_srow[tid] = sorted_rows[r0 + tid];
    __syncthreads();
    const int base  = s_ptr[0];
    const int total = s_ptr[RPB] - base;
    const int start = s_ptr[sub] - base;
    const int end_  = s_ptr[sub + 1] - base;
    const int r     = s_srow[sub];

    float acc[8];
#pragma unroll
    for (int k = 0; k < 8; ++k) acc[k] = 0.f;

    for (int cb2 = 0; cb2 < total; cb2 += MAXE) {
        int cnt = total - cb2;
        if (cnt > MAXE) cnt = MAXE;
        for (int t = tid; t < cnt; t += 256) {
            s_col[t] = csr_col[base + cb2 + t];
            s_val[t] = csr_val[base + cb2 + t];
        }
        __syncthreads();
        const int js = start > cb2 ? start : cb2;
        const int je = end_ < cb2 + cnt ? end_ : cb2 + cnt;
        int j = js;
#pragma unroll 2
        for (; j + 1 < je; j += 2) {
            const int j0 = j - cb2;
            const unsigned o0 = ((unsigned)s_col[j0] << 11) + sl16;
            const unsigned o1 = ((unsigned)s_col[j0 + 1] << 11) + sl16;
            const uint4 x0 = *(const uint4*)(Xb + o0);
            const uint4 x1 = *(const uint4*)(Xb + o1);
            const float v0 = s_val[j0];
            const float v1 = s_val[j0 + 1];
            acc[0] += v0 * bf_lo(x0.x); acc[1] += v0 * bf_hi(x0.x);
            acc[2] += v0 * bf_lo(x0.y); acc[3] += v0 * bf_hi(x0.y);
            acc[4] += v0 * bf_lo(x0.z); acc[5] += v0 * bf_hi(x0.z);
            acc[6] += v0 * bf_lo(x0.w); acc[7] += v0 * bf_hi(x0.w);
            acc[0] += v1 * bf_lo(x1.x); acc[1] += v1 * bf_hi(x1.x);
            acc[2] += v1 * bf_lo(x1.y); acc[3] += v1 * bf_hi(x1.y);
            acc[4] += v1 * bf_lo(x1.z); acc[5] += v1 * bf_hi(x1.z);
            acc[6] += v1 * bf_lo(x1.w); acc[7] += v1 * bf_hi(x1.w);
        }
        if (j < je) {
            const int j0 = j - cb2;
            const unsigned o0 = ((unsigned)s_col[j0] << 11) + sl16;
            const uint4 x0 = *(const uint4*)(Xb + o0);
            const float v0 = s_val[j0];
            acc[0] += v0 * bf_lo(x0.x); acc[1] += v0 * bf_hi(x0.x);
            acc[2] += v0 * bf_lo(x0.y); acc[3] += v0 * bf_hi(x0.y);
            acc[4] += v0 * bf_lo(x0.z); acc[5] += v0 * bf_hi(x0.z);
            acc[6] += v0 * bf_lo(x0.w); acc[7] += v0 * bf_hi(x0.w);
        }
        __syncthreads();
    }

    if (!FINAL) {
        uint4 o;
        o.x = (unsigned int)f2bf(acc[0]) | ((unsigned int)f2bf(acc[1]) << 16);
        o.y = (unsigned int)f2bf(acc[2]) | ((unsigned int)f2bf(acc[3]) << 16);
        o.z = (unsigned int)f2bf(acc[4]) | ((unsigned int)f2bf(acc[5]) << 16);
        o.w = (unsigned int)f2bf(acc[6]) | ((unsigned int)f2bf(acc[7]) << 16);
        Y[(size_t)r * XS8 + slot] = o;
    } else {
        // identity layout: stage 16(d) x 128(n) f32 tile, write transposed + bias
        __syncthreads();                      // all s_col/s_val consumers done
        float* tile = smem;
        const int wbase = sub * TSTRIDE + lane * 8;
        *(float4*)&tile[wbase]     = make_float4(acc[0], acc[1], acc[2], acc[3]);
        *(float4*)&tile[wbase + 4] = make_float4(acc[4], acc[5], acc[6], acc[7]);
        __syncthreads();
        const int n0 = chunk * (N_DIM / NCHUNK);
#pragma unroll
        for (int t = tid; t < 512; t += 256) {
            const int n_loc = t >> 2;         // 0..127
            const int q     = t & 3;          // d quad within the 16-row tile
            float4 o;
            o.x = tile[(q * 4 + 0) * TSTRIDE + n_loc];
            o.y = tile[(q * 4 + 1) * TSTRIDE + n_loc];
            o.z = tile[(q * 4 + 2) * TSTRIDE + n_loc];
            o.w = tile[(q * 4 + 3) * TSTRIDE + n_loc];
            const float4 bv = *(const float4*)&bias[r0 + q * 4];
            o.x += bv.x; o.y += bv.y; o.z += bv.z; o.w += bv.w;
            *(float4*)&out[(size_t)(n0 + n_loc) * D_DIM + r0 + q * 4] = o;
        }
    }
}

extern "C" void kernel_launch(void* const* d_in, const int* in_sizes, int n_in,
                              void* d_out, int out_size, void* d_ws, size_t ws_size,
                              hipStream_t stream) {
    const float* U    = (const float*)d_in[0];
    const float* bias = (const float*)d_in[1];
    const float* vals = (const float*)d_in[2];
    const int*   rows = (const int*)d_in[3];
    const int*   cols = (const int*)d_in[4];
    float* out = (float*)d_out;

    char* ws = (char*)d_ws;
    size_t off = 0;
    char* bufA = ws;                   off += (size_t)D_DIM * N_DIM * 2;   // 8 MB bf16
    char* bufB = ws + off;             off += (size_t)D_DIM * N_DIM * 2;   // 8 MB bf16
    int* row_ptr = (int*)(ws + off);   off += (size_t)K_F * (D_DIM + 1) * 4;
    off = (off + 15) & ~(size_t)15;
    int* cursor  = (int*)(ws + off);   off += (size_t)K_F * D_DIM * 4;
    int* srow    = (int*)(ws + off);   off += (size_t)K_F * D_DIM * 4;
    int*   csr_col = (int*)(ws + off); off += (size_t)K_F * NNZ_F * 4;
    float* csr_val = (float*)(ws + off); off += (size_t)K_F * NNZ_F * 4;

    const int grid_spmm = (D_DIM / RPB) * NCHUNK;   // 256 * 8 = 2048 blocks

    // K1: CSR build (4 blocks FIRST) + transpose U -> A (bf16), fused
    fused_t_build_k<<<T_TILES + K_F, 1024, 0, stream>>>(
        U, (unsigned short*)bufA, rows, row_ptr, cursor, srow);

    // K2: scatter all factors
    scatter_all_k<<<K_F * (NNZ_F / 1024), 1024, 0, stream>>>(rows, cols, vals, cursor,
                                                             csr_col, csr_val);

    // K3: factor 3, A -> B
    spmm_chunk_k<false><<<grid_spmm, 256, 0, stream>>>(
        row_ptr + 3 * (D_DIM + 1), srow + 3 * D_DIM,
        csr_col + 3 * (size_t)NNZ_F, csr_val + 3 * (size_t)NNZ_F,
        (const char*)bufA, (uint4*)bufB, nullptr, nullptr);
    // K4: factor 2, B -> A
    spmm_chunk_k<false><<<grid_spmm, 256, 0, stream>>>(
        row_ptr + 2 * (D_DIM + 1), srow + 2 * D_DIM,
        csr_col + 2 * (size_t)NNZ_F, csr_val + 2 * (size_t)NNZ_F,
        (const char*)bufB, (uint4*)bufA, nullptr, nullptr);
    // K5: factor 1, A -> B
    spmm_chunk_k<false><<<grid_spmm, 256, 0, stream>>>(
        row_ptr + 1 * (D_DIM + 1), srow + 1 * D_DIM,
        csr_col + 1 * (size_t)NNZ_F, csr_val + 1 * (size_t)NNZ_F,
        (const char*)bufA, (uint4*)bufB, nullptr, nullptr);
    // K6: factor 0, B -> out (identity layout; transposed + bias, fused)
    spmm_chunk_k<true><<<grid_spmm, 256, 0, stream>>>(
        row_ptr + 0 * (D_DIM + 1), srow + 0 * D_DIM,
        csr_col + 0 * (size_t)NNZ_F, csr_val + 0 * (size_t)NNZ_F,
        (const char*)bufB, nullptr, out, bias);
}